// Round 7
// baseline (378.638 us; speedup 1.0000x reference)
//
#include <hip/hip_runtime.h>
#include <stdint.h>

typedef _Float16 half8 __attribute__((ext_vector_type(8)));
typedef float floatx16 __attribute__((ext_vector_type(16)));
typedef unsigned long long u64;

#define ALPHA_ 1.0f
#define BETA_ 0.25f
#define NUM_EMBEDS 8192
#define EMBED_DIM 512
#define B_ 32
#define T_ 256
#define N_TOK 8192
#define THR_GAP 0.01f

// ---------------- ws layout (bytes) ----------------
// wexact   @ 0        (64 KB)  u64: monokey<<32 | code
// cnorm    @ 65536    (32 KB)
// counts   @ 98304    (32 KB)
// sse      @ 131072   (4 B)
// nflag    @ 131076   (4 B)
// worklist @ 131080   (32 KB)
// slot     @ 1  MB    (4 MB)   u64 [64 chunks][8192 tok]: mono<<32 | code<<16 | d16
// cb_i     @ 6  MB    (16 MB)  f16 packed codebook (h + direct residual), seg layout
// zt_i     @ 22 MB    (16 MB)  f16 packed -2*z^T
// ---------------------------------------------------
// packed row (1024 halves): ss in [0,32): 32 halves at ss*32:
//   [p0 hf0 (8)][p0 hf1 (8)][p1 hf0 (8)][p1 hf1 (8)], elems k = ss*16 + hfp*8 + [0,8)

typedef __attribute__((address_space(1))) const void ga_void;
typedef __attribute__((address_space(3))) void ls_void;
__device__ __forceinline__ void gl_lds16(const void* g, void* l) {
    __builtin_amdgcn_global_load_lds((ga_void*)g, (ls_void*)l, 16, 0, 0);
}

__device__ __forceinline__ uint32_t mono(float s) {
    uint32_t u = __float_as_uint(s);
    return (u & 0x80000000u) ? ~u : (u | 0x80000000u);
}
__device__ __forceinline__ float unmono(uint32_t v) {
    return __uint_as_float((v & 0x80000000u) ? (v ^ 0x80000000u) : ~v);
}

// fused: codebook pack (blocks 0..2047), z pack (2048..2175), ws init (2176..2207)
__global__ void pack_kernel(const float* __restrict__ cb, const float* __restrict__ z,
                            _Float16* __restrict__ cb_i, _Float16* __restrict__ zt_i,
                            float* __restrict__ cnorm, u64* __restrict__ wexact,
                            int* __restrict__ counts, float* __restrict__ sse,
                            int* __restrict__ nflag) {
    const int bx = blockIdx.x;
    const int tid = threadIdx.x;
    if (bx < 2048) {
        int row = bx * 4 + (tid >> 6);
        int lane = tid & 63;
        const float* src = cb + (size_t)row * EMBED_DIM + lane * 8;
        float4 v0 = *(const float4*)src;
        float4 v1 = *(const float4*)(src + 4);
        float x[8] = {v0.x, v0.y, v0.z, v0.w, v1.x, v1.y, v1.z, v1.w};
        half8 hh, mm;
        float s = 0.f;
#pragma unroll
        for (int j = 0; j < 8; ++j) {
            s += x[j] * x[j];
            _Float16 hv = (_Float16)x[j];
            hh[j] = hv;
            mm[j] = (_Float16)(x[j] - (float)hv);
        }
        _Float16* dst = cb_i + (size_t)row * 1024 + (lane >> 1) * 32 + (lane & 1) * 8;
        *(half8*)dst = hh;
        *(half8*)(dst + 16) = mm;
#pragma unroll
        for (int d = 32; d; d >>= 1) s += __shfl_xor(s, d, 64);
        if (lane == 0) cnorm[row] = s;
    } else if (bx < 2176) {
        int bz = bx - 2048;
        int lane = tid & 63, ds = tid >> 6;
        int b = bz >> 2;
        int t = ((bz & 3) << 6) + lane;
        size_t n = (size_t)b * T_ + t;
        for (int g = 0; g < 16; ++g) {
            int d0 = g * 32 + ds * 8;
            const float* src = z + ((size_t)b * EMBED_DIM + d0) * T_ + t;
            half8 hh, mm;
#pragma unroll
            for (int j = 0; j < 8; ++j) {
                float x = -2.0f * src[(size_t)j * T_];
                _Float16 hv = (_Float16)x;
                hh[j] = hv;
                mm[j] = (_Float16)(x - (float)hv);
            }
            int gg = g * 4 + ds;
            _Float16* dst = zt_i + n * 1024 + (gg >> 1) * 32 + (gg & 1) * 8;
            *(half8*)dst = hh;
            *(half8*)(dst + 16) = mm;
        }
    } else {
        int i = bx - 2176;
        wexact[i * 256 + tid] = ~0ULL;
        counts[i * 256 + tid] = 0;
        if (i == 0 && tid == 0) { *sse = 0.f; *nflag = 0; }
    }
}

// ---- pass 1: merged-acc 2-plane argmin GEMM, 128 codes x 256 tokens, BK=16, dbuf ----
#define MFMA16(a, b, c) __builtin_amdgcn_mfma_f32_32x32x16_f16(a, b, c, 0, 0, 0)

__global__ __launch_bounds__(256, 2) void argmin_kernel(
    const _Float16* __restrict__ cb_i, const _Float16* __restrict__ zt_i,
    const float* __restrict__ cnorm, u64* __restrict__ slot) {
    // halves: A0[0,4096) A1[4096,8192) B0[8192,16384) B1[16384,24576)
    __shared__ _Float16 smem[24576];
    __shared__ u64 sK[256];
    __shared__ float sV1[256], sV2[256];
    const int tid = threadIdx.x;
    const int l = tid & 63;
    const int wv = tid >> 6;
    const int l31 = l & 31;
    const int hf = l >> 5;
    const int wp = wv >> 1, wq = wv & 1;
    const int n0 = blockIdx.x * 256;
    const int c0 = blockIdx.y * 128;

    // staging descriptors: 24 x 1KB instrs (A:8, B:16), 6 per wave
    const _Float16* gptr[6];
    int lofs[6], bmul[6];
#pragma unroll
    for (int j = 0; j < 6; ++j) {
        int id = wv * 6 + j;
        if (id < 8) {
            int rp = id * 4 + (l >> 4);
            int lid = (l & 15) ^ (rp & 15);
            gptr[j] = cb_i + (size_t)(c0 + (lid >> 2) * 32 + rp) * 1024 + (lid & 3) * 8;
            lofs[j] = id * 512 + l * 8;
            bmul[j] = 4096;
        } else {
            int bid = id - 8;
            int rp = bid * 4 + (l >> 4);
            int lid = (l & 15) ^ (rp & 15);
            gptr[j] = zt_i + (size_t)(n0 + (lid >> 2) * 64 + rp) * 1024 + (lid & 3) * 8;
            lofs[j] = 8192 + bid * 512 + l * 8;
            bmul[j] = 8192;
        }
    }
    auto stagefull = [&](int buf, int ss) {
        const int ga = ss * 32;
#pragma unroll
        for (int j = 0; j < 6; ++j)
            gl_lds16(gptr[j] + ga, smem + lofs[j] + buf * bmul[j]);
    };

    // fragment LDS offsets (2-way-max bank aliasing via 16-slot XOR swizzle)
    int aoff[2][2], boff[4][2];
#pragma unroll
    for (int pi = 0; pi < 2; ++pi)
#pragma unroll
        for (int p = 0; p < 2; ++p) {
            int lid = (wp * 2 + pi) * 4 + p * 2 + hf;
            aoff[pi][p] = l31 * 128 + (lid ^ (l31 & 15)) * 8;
        }
#pragma unroll
    for (int qi = 0; qi < 4; ++qi)
#pragma unroll
        for (int p = 0; p < 2; ++p) {
            int lid = (wq * 2 + (qi >> 1)) * 4 + p * 2 + hf;
            boff[qi][p] = 8192 + ((qi & 1) * 32 + l31) * 128 + (lid ^ (l31 & 15)) * 8;
        }

    floatx16 acc[2][4];
#pragma unroll
    for (int pi = 0; pi < 2; ++pi)
#pragma unroll
        for (int qi = 0; qi < 4; ++qi)
#pragma unroll
            for (int r = 0; r < 16; ++r) acc[pi][qi][r] = 0.f;

    stagefull(0, 0);
    __syncthreads();
    for (int ss = 0; ss < 32; ++ss) {
        const int buf = ss & 1;
        const int ab = buf * 4096, bb = buf * 8192;
        half8 Ah[2], Am[2], Bh[4], Bm[4];
#pragma unroll
        for (int pi = 0; pi < 2; ++pi) {
            Ah[pi] = *(const half8*)(smem + aoff[pi][0] + ab);
            Am[pi] = *(const half8*)(smem + aoff[pi][1] + ab);
        }
#pragma unroll
        for (int qi = 0; qi < 4; ++qi) {
            Bh[qi] = *(const half8*)(smem + boff[qi][0] + bb);
            Bm[qi] = *(const half8*)(smem + boff[qi][1] + bb);
        }
        if (ss < 31) stagefull(buf ^ 1, ss + 1);
#pragma unroll
        for (int pi = 0; pi < 2; ++pi)
#pragma unroll
            for (int qi = 0; qi < 4; ++qi) {
                acc[pi][qi] = MFMA16(Ah[pi], Bh[qi], acc[pi][qi]);
                acc[pi][qi] = MFMA16(Am[pi], Bh[qi], acc[pi][qi]);
                acc[pi][qi] = MFMA16(Ah[pi], Bm[qi], acc[pi][qi]);
            }
        __syncthreads();
    }

    // epilogue: per (lane, qi) -> one token, 32 codes in this wave's wp-half
    u64 qk[4];
    float qv1[4], qv2[4];
#pragma unroll
    for (int qi = 0; qi < 4; ++qi) {
        u64 m1k = ~0ULL;
        float m1v = 3.4e38f, m2 = 3.4e38f;
#pragma unroll
        for (int pi = 0; pi < 2; ++pi)
#pragma unroll
            for (int g = 0; g < 4; ++g) {
                const int cb4 = c0 + wp * 64 + pi * 32 + g * 8 + hf * 4;
                float4 cn = *(const float4*)(cnorm + cb4);
                const floatx16& A = acc[pi][qi];
                float sv[4] = {cn.x + A[g * 4 + 0], cn.y + A[g * 4 + 1],
                               cn.z + A[g * 4 + 2], cn.w + A[g * 4 + 3]};
#pragma unroll
                for (int q = 0; q < 4; ++q) {
                    u64 key = ((u64)mono(sv[q]) << 32) | (uint32_t)(cb4 + q);
                    if (key < m1k) { m2 = m1v; m1v = sv[q]; m1k = key; }
                    else m2 = fminf(m2, sv[q]);
                }
            }
        // hf-pair merge (lane ^ 32 holds same token, other code rows)
        u64 ok = __shfl_xor(m1k, 32, 64);
        float ov = __shfl_xor(m1v, 32, 64);
        float om2 = __shfl_xor(m2, 32, 64);
        if (ok < m1k) { m2 = fminf(fminf(m2, om2), m1v); m1v = ov; m1k = ok; }
        else m2 = fminf(fminf(m2, om2), ov);
        qk[qi] = m1k; qv1[qi] = m1v; qv2[qi] = m2;
    }
    // cross-wave (wp) merge: wp=1 publishes, wp=0 merges + stores the slot
    if (wp == 1 && hf == 0) {
#pragma unroll
        for (int qi = 0; qi < 4; ++qi) {
            const int tl = wq * 128 + qi * 32 + l31;
            sK[tl] = qk[qi]; sV1[tl] = qv1[qi]; sV2[tl] = qv2[qi];
        }
    }
    __syncthreads();
    if (wp == 0 && hf == 0) {
#pragma unroll
        for (int qi = 0; qi < 4; ++qi) {
            const int tl = wq * 128 + qi * 32 + l31;
            u64 m1k = qk[qi]; float m1v = qv1[qi], m2 = qv2[qi];
            u64 ok = sK[tl]; float ov = sV1[tl], om2 = sV2[tl];
            if (ok < m1k) { m2 = fminf(fminf(m2, om2), m1v); m1v = ov; m1k = ok; }
            else m2 = fminf(fminf(m2, om2), ov);
            uint32_t code = (uint32_t)m1k & 0x1FFFu;
            uint32_t d16 = (uint32_t)__builtin_bit_cast(unsigned short, (_Float16)(m2 - m1v));
            slot[((size_t)blockIdx.y << 13) + n0 + tl] =
                (m1k & 0xFFFFFFFF00000000ULL) | ((u64)code << 16) | d16;
        }
    }
}

// ---- combine: merge 64 chunk summaries per token; gap-test; worklist unsafe ----
__global__ void combine_kernel(const u64* __restrict__ slot, u64* __restrict__ wexact,
                               int* __restrict__ worklist, int* __restrict__ nflag) {
    int tok = blockIdx.x * 256 + threadIdx.x;
    u64 g1 = ~0ULL;
    float g1v = 3.4e38f, g2 = 3.4e38f;
    for (int c = 0; c < 64; ++c) {
        u64 v = slot[((size_t)c << 13) + tok];
        float kv = unmono((uint32_t)(v >> 32));
        float d = (float)__builtin_bit_cast(_Float16, (unsigned short)(v & 0xffff));
        if (v < g1) { g2 = fminf(g2, g1v); g1 = v; g1v = kv; }
        else g2 = fminf(g2, kv);
        g2 = fminf(g2, kv + d);
    }
    if (g2 - g1v > THR_GAP)
        wexact[tok] = (g1 & 0xFFFFFFFF00000000ULL) | ((g1 >> 16) & 0x1FFFULL);
    else { int i = atomicAdd(nflag, 1); if (i < 8192) worklist[i] = tok; }
}

// ---- fallback: exact fp32 rescore of flagged tokens ----
__global__ void fallback_kernel(const float* __restrict__ z, const float* __restrict__ cb,
                                const float* __restrict__ cnorm,
                                const int* __restrict__ worklist, const int* __restrict__ nflag,
                                u64* __restrict__ wexact) {
    int n = *nflag;
    if (n > 8192) n = 8192;
    const int l = threadIdx.x & 63, wv = threadIdx.x >> 6;
    const int cbase = blockIdx.x * 128;
    for (int fi = blockIdx.y; fi < n; fi += gridDim.y) {
        int tok = worklist[fi];
        int b = tok >> 8, t = tok & 255;
        const float* zp = z + ((size_t)b * EMBED_DIM) * T_ + t;
        float zr[8];
#pragma unroll
        for (int j = 0; j < 8; ++j) zr[j] = zp[(size_t)(l * 8 + j) * T_];
        u64 m1 = ~0ULL;
        for (int j = 0; j < 32; ++j) {
            int c = cbase + wv + j * 4;
            const float* cp = cb + (size_t)c * EMBED_DIM + l * 8;
            float4 a = *(const float4*)cp, bb = *(const float4*)(cp + 4);
            float dot = zr[0] * a.x + zr[1] * a.y + zr[2] * a.z + zr[3] * a.w +
                        zr[4] * bb.x + zr[5] * bb.y + zr[6] * bb.z + zr[7] * bb.w;
#pragma unroll
            for (int m = 32; m; m >>= 1) dot += __shfl_xor(dot, m, 64);
            if (l == 0) {
                float s = cnorm[c] - 2.0f * dot;
                u64 key = ((u64)mono(s) << 32) | (uint32_t)c;
                if (key < m1) m1 = key;
            }
        }
        if (l == 0) atomicMin(&wexact[tok], m1);
    }
}

__global__ void gather_kernel(const float* __restrict__ z, const float* __restrict__ cb,
                              const u64* __restrict__ wexact,
                              float* __restrict__ out, int* __restrict__ counts,
                              float* __restrict__ sse_acc) {
    __shared__ unsigned int sIdx[64];
    __shared__ float red[4];
    const int tid = threadIdx.x;
    const int n0 = blockIdx.x * 64;
    const int b = n0 >> 8;
    const int t0 = n0 & 255;
    if (tid < 64) {
        unsigned int idx = (unsigned int)(wexact[n0 + tid] & 0x1FFFULL);
        sIdx[tid] = idx;
        atomicAdd(&counts[idx], 1);
    }
    __syncthreads();
    const int w = tid >> 6;
    const int lane = tid & 63;
    const float* crow = cb + (size_t)sIdx[lane] * EMBED_DIM;
    const size_t base = ((size_t)b * EMBED_DIM) * T_ + (size_t)(t0 + lane);
    float sse = 0.f;
    for (int d = w; d < EMBED_DIM; d += 4) {
        float v = crow[d];
        size_t o = base + (size_t)d * T_;
        float diff = v - z[o];
        out[o] = v;
        sse += diff * diff;
    }
    for (int m = 32; m; m >>= 1) sse += __shfl_xor(sse, m, 64);
    if (lane == 0) red[w] = sse;
    __syncthreads();
    if (tid == 0) atomicAdd(sse_acc, red[0] + red[1] + red[2] + red[3]);
}

__global__ void finalize_kernel(const int* __restrict__ counts,
                                const float* __restrict__ sse_acc,
                                float* __restrict__ out) {
    __shared__ float red[4];
    const int tid = threadIdx.x;
    float e = 0.f;
    for (int k = tid; k < NUM_EMBEDS; k += 256) {
        float p = (float)counts[k] * (1.0f / (float)N_TOK);
        e += p * logf(p + 1e-10f);
    }
    for (int m = 32; m; m >>= 1) e += __shfl_xor(e, m, 64);
    if ((tid & 63) == 0) red[tid >> 6] = e;
    __syncthreads();
    if (tid == 0) {
        float ent = red[0] + red[1] + red[2] + red[3];
        size_t off = (size_t)B_ * EMBED_DIM * T_;
        out[off + 0] = (ALPHA_ * BETA_) * sse_acc[0] / (float)((size_t)N_TOK * EMBED_DIM);
        out[off + 1] = expf(-ent);
    }
}

extern "C" void kernel_launch(void* const* d_in, const int* in_sizes, int n_in,
                              void* d_out, int out_size, void* d_ws, size_t ws_size,
                              hipStream_t stream) {
    const float* z = (const float*)d_in[0];
    const float* cb = (const float*)d_in[1];
    float* out = (float*)d_out;
    char* ws = (char*)d_ws;
    u64* wexact = (u64*)ws;
    float* cnorm = (float*)(ws + 65536);
    int* counts = (int*)(ws + 98304);
    float* sse = (float*)(ws + 131072);
    int* nflag = (int*)(ws + 131076);
    int* worklist = (int*)(ws + 131080);
    u64* slot = (u64*)(ws + (1ull << 20));
    _Float16* cb_i = (_Float16*)(ws + (6ull << 20));
    _Float16* zt_i = (_Float16*)(ws + (22ull << 20));

    pack_kernel<<<2208, 256, 0, stream>>>(cb, z, cb_i, zt_i, cnorm, wexact, counts, sse, nflag);
    argmin_kernel<<<dim3(N_TOK / 256, NUM_EMBEDS / 128), 256, 0, stream>>>(cb_i, zt_i, cnorm, slot);
    combine_kernel<<<N_TOK / 256, 256, 0, stream>>>(slot, wexact, worklist, nflag);
    fallback_kernel<<<dim3(64, 16), 256, 0, stream>>>(z, cb, cnorm, worklist, nflag, wexact);
    gather_kernel<<<N_TOK / 64, 256, 0, stream>>>(z, cb, wexact, out, counts, sse);
    finalize_kernel<<<1, 256, 0, stream>>>(counts, sse, out);
}